// Round 1
// baseline (326.757 us; speedup 1.0000x reference)
//
#include <hip/hip_runtime.h>

// ---------------- problem constants ----------------
#define N_ROWS   131072     // 32*64*64
#define DIM      64
#define NE       512
#define DECAYF   0.99f
#define OMDECAY  0.01f
#define EPSF     1e-5f

// ---------------- d_out offsets (floats) ----------------
#define Q_OFF    0            // 8388608
#define DIFF_OFF 8388608      // 1
#define IND_OFF  8388609      // 131072
#define CS_OFF   8519681      // 512
#define AVG_OFF  8520193      // 32768
#define EMB_OFF  8552961      // 32768

// ---------------- ws offsets (floats) ----------------
#define WS_ET     0                       // 32768  : embed transposed [512][64]
#define WS_ENORM  32768                   // 512    : ||E_j||^2
#define WS_DIFF   33280                   // 1      : diff accumulator (float)
#define WS_RCNT   33281                   // 1      : refine counter (int)
#define WS_IDX    33282                   // 131072 : chosen index per row (int)
#define WS_RLIST  164354                  // 131072 : refine row list (int)
#define WS_PART   295426                  // nslices * 33280 partial sums
#define PART_STRIDE 33280                 // 32768 esum + 512 counts

// ============================================================
// Kernel A: build ET (embed transposed), enorm; zero small accums;
// optionally zero partial slices (fallback path).
// ============================================================
__global__ __launch_bounds__(64) void prep_kernel(const float* __restrict__ embed,
                                                  float* __restrict__ ws,
                                                  int zero_cnt) {
    int j = blockIdx.x;      // 0..511
    int d = threadIdx.x;     // 0..63
    float v = embed[d * NE + j];
    ws[WS_ET + j * DIM + d] = v;
    float sq = v * v;
    #pragma unroll
    for (int off = 32; off > 0; off >>= 1) sq += __shfl_down(sq, off, 64);
    if (d == 0) ws[WS_ENORM + j] = sq;
    if (j == 0 && d == 0) {
        ws[WS_DIFF] = 0.0f;
        reinterpret_cast<int*>(ws)[WS_RCNT] = 0;
    }
    // fallback-path zeroing of partial slices
    int gid = blockIdx.x * 64 + threadIdx.x;     // 0..32767
    for (int e = gid; e < zero_cnt; e += 512 * 64)
        ws[WS_PART + e] = 0.0f;
}

// ============================================================
// Kernel B: fused distance + argmin (fp32, with second-min gap check).
// Block: 256 threads, 64 rows x all 512 cols (8 j-tiles of 64).
// dist_j = ||E_j||^2 - 2 f.E_j   (row norm dropped: constant per row)
// ============================================================
#define BROWS 64
#define LDP   68   // padded leading dim, keeps float4 alignment, odd/4 bank spread

__global__ __launch_bounds__(256) void dist_kernel(const float* __restrict__ input,
                                                   const float* __restrict__ embed,
                                                   float* __restrict__ ws) {
    __shared__ float fT[DIM * LDP];            // [d][row] transposed input tile
    __shared__ float Et[DIM * LDP + 64];       // [d][jc] embed tile + enorm row

    const int tid  = threadIdx.x;
    const int row0 = blockIdx.x * BROWS;

    // stage transposed input tile: fT[d][r] = input[row0+r][d]
    {
        int d  = tid & 63;
        int rb = tid >> 6;
        #pragma unroll
        for (int p = 0; p < 16; p++) {
            int r = p * 4 + rb;
            fT[d * LDP + r] = input[(size_t)(row0 + r) * DIM + d];
        }
    }

    const int rg = tid >> 4;   // 0..15 -> rows rg*4..rg*4+3
    const int cg = tid & 15;   // 0..15 -> cols cg*4..cg*4+3 within j-tile

    float m1[4], m2[4];
    int   j1[4];
    #pragma unroll
    for (int i = 0; i < 4; i++) { m1[i] = 3.4e38f; m2[i] = 3.4e38f; j1[i] = 0; }

    for (int jt = 0; jt < 8; jt++) {
        const int j0 = jt * 64;
        __syncthreads();   // protect Et from previous iteration's readers
        {
            int jc = tid & 63;
            int db = tid >> 6;
            #pragma unroll
            for (int p = 0; p < 16; p++) {
                int d = p * 4 + db;
                Et[d * LDP + jc] = embed[d * NE + j0 + jc];
            }
            if (tid < 64) Et[DIM * LDP + tid] = ws[WS_ENORM + j0 + tid];
        }
        __syncthreads();

        float acc[4][4];
        #pragma unroll
        for (int i = 0; i < 4; i++)
            #pragma unroll
            for (int k = 0; k < 4; k++) acc[i][k] = 0.0f;

        const float* fp = &fT[rg * 4];
        const float* ep = &Et[cg * 4];
        #pragma unroll 4
        for (int d = 0; d < DIM; d++) {
            float4 fv = *reinterpret_cast<const float4*>(fp + d * LDP);
            float4 ev = *reinterpret_cast<const float4*>(ep + d * LDP);
            float fa[4] = {fv.x, fv.y, fv.z, fv.w};
            float ea[4] = {ev.x, ev.y, ev.z, ev.w};
            #pragma unroll
            for (int i = 0; i < 4; i++)
                #pragma unroll
                for (int k = 0; k < 4; k++)
                    acc[i][k] = fmaf(fa[i], ea[k], acc[i][k]);
        }

        // epilogue: update per-row (min1, min2, idx1); j ascending within thread
        #pragma unroll
        for (int k = 0; k < 4; k++) {
            int   j  = j0 + cg * 4 + k;
            float en = Et[DIM * LDP + cg * 4 + k];
            #pragma unroll
            for (int i = 0; i < 4; i++) {
                float dist = fmaf(-2.0f, acc[i][k], en);
                if (dist < m1[i]) { m2[i] = m1[i]; m1[i] = dist; j1[i] = j; }
                else if (dist < m2[i]) { m2[i] = dist; }
            }
        }
    }

    // cross-lane reduce over the 16 col-groups (lanes rg*16+cg share a wave)
    #pragma unroll
    for (int off = 1; off < 16; off <<= 1) {
        #pragma unroll
        for (int i = 0; i < 4; i++) {
            float b1 = __shfl_xor(m1[i], off, 64);
            float b2 = __shfl_xor(m2[i], off, 64);
            int   bj = __shfl_xor(j1[i], off, 64);
            float a1 = m1[i];
            float mx = fmaxf(a1, b1);
            float nm2 = fminf(fminf(m2[i], b2), mx);
            bool takeB = (b1 < a1) || (b1 == a1 && bj < j1[i]);
            m1[i] = takeB ? b1 : a1;
            j1[i] = takeB ? bj : j1[i];
            m2[i] = nm2;
        }
    }

    if (cg == 0) {
        #pragma unroll
        for (int i = 0; i < 4; i++) {
            int r = row0 + rg * 4 + i;
            reinterpret_cast<int*>(ws)[WS_IDX + r] = j1[i];
            if (m2[i] - m1[i] < 0.02f) {   // near-tie: fp64 re-resolve
                int pos = atomicAdd(reinterpret_cast<int*>(ws) + WS_RCNT, 1);
                reinterpret_cast<int*>(ws)[WS_RLIST + pos] = r;
            }
        }
    }
}

// ============================================================
// Kernel B2: fp64 re-resolution of near-tie rows (rare, ~0.3%).
// One wave per flagged row; lane handles 8 codes.
// ============================================================
__global__ __launch_bounds__(64) void refine_kernel(const float* __restrict__ input,
                                                    float* __restrict__ ws) {
    const int cnt  = reinterpret_cast<const int*>(ws)[WS_RCNT];
    const int lane = threadIdx.x;
    for (int ii = blockIdx.x; ii < cnt; ii += gridDim.x) {
        const int r = reinterpret_cast<const int*>(ws)[WS_RLIST + ii];
        double bd = 1e300;
        int    bj = 0;
        for (int kk = 0; kk < 8; kk++) {
            int j = kk * 64 + lane;
            const float* ep = &ws[WS_ET + j * DIM];
            double s = 0.0, s2 = 0.0;
            #pragma unroll 8
            for (int d = 0; d < DIM; d++) {
                double e = (double)ep[d];
                double f = (double)input[(size_t)r * DIM + d];
                s  = fma(f, e, s);
                s2 = fma(e, e, s2);
            }
            double dist = s2 - 2.0 * s;
            if (dist < bd || (dist == bd && j < bj)) { bd = dist; bj = j; }
        }
        #pragma unroll
        for (int off = 32; off > 0; off >>= 1) {
            double od = __shfl_down(bd, off, 64);
            int    oj = __shfl_down(bj, off, 64);
            if (od < bd || (od == bd && oj < bj)) { bd = od; bj = oj; }
        }
        if (lane == 0) reinterpret_cast<int*>(ws)[WS_IDX + r] = bj;
    }
}

// ============================================================
// Kernel D: quantize gather + diff + embed_ind + LDS scatter-accumulate.
// 256 blocks x 256 threads; each block owns 512 contiguous rows.
// ============================================================
__global__ __launch_bounds__(256) void scatter_kernel(const float* __restrict__ input,
                                                      float* __restrict__ ws,
                                                      float* __restrict__ out,
                                                      int nslices) {
    __shared__ float loc[NE * DIM];   // [j][d], 128 KiB
    __shared__ float locc[NE];
    __shared__ float wsum[4];

    const int tid = threadIdx.x;
    for (int e = tid; e < NE * DIM; e += 256) loc[e] = 0.0f;
    for (int e = tid; e < NE; e += 256) locc[e] = 0.0f;
    __syncthreads();

    const int lane = tid & 63;
    const int w    = tid >> 6;
    const int base = blockIdx.x * 512;
    float dacc = 0.0f;

    for (int it = 0; it < 128; it++) {
        int r = base + it * 4 + w;
        int j = reinterpret_cast<const int*>(ws)[WS_IDX + r];
        float in = input[(size_t)r * DIM + lane];
        float q  = ws[WS_ET + j * DIM + lane];
        out[Q_OFF + (size_t)r * DIM + lane] = q;
        float df = q - in;
        dacc = fmaf(df, df, dacc);
        atomicAdd(&loc[j * DIM + lane], in);
        if (lane == 0) {
            atomicAdd(&locc[j], 1.0f);
            out[IND_OFF + r] = (float)j;
        }
    }
    __syncthreads();

    // flush partials
    if (nslices == 256) {
        float* part = ws + WS_PART + (size_t)blockIdx.x * PART_STRIDE;
        for (int e = tid; e < NE * DIM; e += 256) part[e] = loc[e];
        for (int e = tid; e < NE; e += 256) part[NE * DIM + e] = locc[e];
    } else {
        float* part = ws + WS_PART + (size_t)(blockIdx.x % nslices) * PART_STRIDE;
        for (int e = tid; e < NE * DIM; e += 256) atomicAdd(&part[e], loc[e]);
        for (int e = tid; e < NE; e += 256) atomicAdd(&part[NE * DIM + e], locc[e]);
    }

    // diff reduction
    #pragma unroll
    for (int off = 32; off > 0; off >>= 1) dacc += __shfl_down(dacc, off, 64);
    if (lane == 0) wsum[w] = dacc;
    __syncthreads();
    if (tid == 0)
        atomicAdd(&ws[WS_DIFF], wsum[0] + wsum[1] + wsum[2] + wsum[3]);
}

// ============================================================
// Kernel E1: reduce partials; write new_cluster_size + new_embed_avg.
// ============================================================
__global__ __launch_bounds__(256) void reduce_kernel(const float* __restrict__ cluster_size,
                                                     const float* __restrict__ embed_avg,
                                                     const float* __restrict__ ws,
                                                     float* __restrict__ out,
                                                     int nslices) {
    int e = blockIdx.x * 256 + threadIdx.x;
    if (e >= PART_STRIDE) return;
    float s = 0.0f;
    const float* p = ws + WS_PART + e;
    for (int b = 0; b < nslices; b++) s += p[(size_t)b * PART_STRIDE];
    if (e < NE * DIM) {
        int j = e >> 6, d = e & 63;
        out[AVG_OFF + d * NE + j] = fmaf(embed_avg[d * NE + j], DECAYF, OMDECAY * s);
    } else {
        int j = e - NE * DIM;
        out[CS_OFF + j] = fmaf(cluster_size[j], DECAYF, OMDECAY * s);
    }
}

// ============================================================
// Kernel E2: n = sum(new_cluster_size); cs; new_embed; diff finalize.
// ============================================================
__global__ __launch_bounds__(512) void finalize_kernel(const float* __restrict__ ws,
                                                       float* __restrict__ out) {
    __shared__ float cs_sh[NE];
    __shared__ float red[8];
    const int t = threadIdx.x;

    float v = out[CS_OFF + t];
    float s = v;
    #pragma unroll
    for (int off = 32; off > 0; off >>= 1) s += __shfl_down(s, off, 64);
    if ((t & 63) == 0) red[t >> 6] = s;
    __syncthreads();
    float n = red[0] + red[1] + red[2] + red[3] + red[4] + red[5] + red[6] + red[7];

    float cs = (v + EPSF) / (n + (float)NE * EPSF) * n;
    cs_sh[t] = cs;
    __syncthreads();

    for (int e = t; e < NE * DIM; e += 512) {
        int j = e & (NE - 1);
        out[EMB_OFF + e] = out[AVG_OFF + e] / cs_sh[j];
    }
    if (t == 0) out[DIFF_OFF] = ws[WS_DIFF] * (1.0f / 8388608.0f);
}

// ============================================================
extern "C" void kernel_launch(void* const* d_in, const int* in_sizes, int n_in,
                              void* d_out, int out_size, void* d_ws, size_t ws_size,
                              hipStream_t stream) {
    const float* input        = (const float*)d_in[0];
    const float* embed        = (const float*)d_in[1];
    const float* cluster_size = (const float*)d_in[2];
    const float* embed_avg    = (const float*)d_in[3];
    float* out = (float*)d_out;
    float* ws  = (float*)d_ws;

    // how many partial slices fit in ws?
    int nslices = 256;
    size_t needed = ((size_t)WS_PART + 256ull * PART_STRIDE) * 4ull;
    if (ws_size < needed) {
        size_t avail_f = ws_size / 4;
        size_t room = (avail_f > WS_PART) ? (avail_f - WS_PART) : 0;
        long long k = (long long)(room / PART_STRIDE);
        nslices = (int)(k < 1 ? 1 : (k > 256 ? 256 : k));
    }
    int zero_cnt = (nslices == 256) ? 0 : nslices * PART_STRIDE;

    prep_kernel<<<512, 64, 0, stream>>>(embed, ws, zero_cnt);
    dist_kernel<<<N_ROWS / BROWS, 256, 0, stream>>>(input, embed, ws);
    refine_kernel<<<512, 64, 0, stream>>>(input, ws);
    scatter_kernel<<<256, 256, 0, stream>>>(input, ws, out, nslices);
    reduce_kernel<<<(PART_STRIDE + 255) / 256, 256, 0, stream>>>(cluster_size, embed_avg, ws, out, nslices);
    finalize_kernel<<<1, 512, 0, stream>>>(ws, out);
}

// Round 2
// 195.980 us; speedup vs baseline: 1.6673x; 1.6673x over previous
//
#include <hip/hip_runtime.h>

typedef __attribute__((ext_vector_type(8))) short short8_t;
typedef __attribute__((ext_vector_type(4))) float f32x4;

// ---------------- problem constants ----------------
#define N_ROWS   131072     // 32*64*64
#define DIM      64
#define NE       512
#define DECAYF   0.99f
#define OMDECAY  0.01f
#define EPSF     1e-5f
#define GAP_THR  0.02f

// ---------------- d_out offsets (floats) ----------------
#define Q_OFF    0            // 8388608
#define DIFF_OFF 8388608      // 1
#define IND_OFF  8388609      // 131072
#define CS_OFF   8519681      // 512
#define AVG_OFF  8520193      // 32768
#define EMB_OFF  8552961      // 32768

// ---------------- ws offsets (floats) ----------------
#define WS_ET     0            // 32768 : ET fp32 [code][dim]
#define WS_ENORM  32768        // 512   : ||E_j||^2 fp32
#define WS_EN64   33280        // 1024  : ||E_j||^2 fp64 (512 doubles, 8B aligned)
#define WS_CSDIV  34304        // 512   : cs divisor
#define WS_DIFF   34816        // 1
#define WS_RCNT   34817        // 1 (int)
#define WS_IDX    34818        // 131072 (int)
#define WS_RLIST  165890       // 131072 (int)
#define WS_BH     296964       // 16384 floats = 32768 ushort: packed bf16 hi B-fragments
#define WS_BL     313348       // 16384 floats = 32768 ushort: packed bf16 lo B-fragments
#define WS_PART   329732       // nslices * PART_STRIDE
#define PART_STRIDE 33280      // 32768 esum + 512 counts
#define NBLK_SC  256           // scatter blocks (= max slices)

__device__ __forceinline__ ushort f32_to_bf16_rn(float f) {
    unsigned u = __float_as_uint(f);
    unsigned r = (u + 0x7FFFu + ((u >> 16) & 1u)) >> 16;
    return (ushort)r;
}
__device__ __forceinline__ float bf16_to_f32(ushort h) {
    return __uint_as_float(((unsigned)h) << 16);
}

// ============================================================
// prep1: transpose embed -> ET fp32; build packed bf16 hi/lo B-fragment
// images in per-lane register order; zero small accumulators.
// grid 64 blocks (d) x 512 threads (c): coalesced embed read.
// ============================================================
__global__ __launch_bounds__(512) void prep1_kernel(const float* __restrict__ embed,
                                                    float* __restrict__ ws,
                                                    int zero_cnt) {
    const int d = blockIdx.x;    // dim 0..63
    const int c = threadIdx.x;   // code 0..511
    float v = embed[d * NE + c];
    ws[WS_ET + c * DIM + d] = v;

    ushort hb = f32_to_bf16_rn(v);
    float  lf = v - bf16_to_f32(hb);
    ushort lb = f32_to_bf16_rn(lf);

    // fragment order: tile T=c>>4, n=c&15, kstep s=d>>5, k8=(d>>3)&3, j=d&7
    const int T  = c >> 4;
    const int n  = c & 15;
    const int s  = d >> 5;
    const int k8 = (d >> 3) & 3;
    const int j  = d & 7;
    const int l  = k8 * 16 + n;
    const int idx = (T * 2 + s) * 512 + l * 8 + j;
    ((ushort*)(ws + WS_BH))[idx] = hb;
    ((ushort*)(ws + WS_BL))[idx] = lb;

    if (d == 0 && c == 0) {
        ws[WS_DIFF] = 0.0f;
        ((int*)ws)[WS_RCNT] = 0;
    }
    // fallback-path zeroing of partial slices
    int gid = blockIdx.x * 512 + threadIdx.x;   // 0..32767
    for (int e = gid; e < zero_cnt; e += 64 * 512)
        ws[WS_PART + e] = 0.0f;
}

// ============================================================
// prep2: enorm fp32 + fp64 from ET (coalesced). wave per code.
// ============================================================
__global__ __launch_bounds__(256) void prep2_kernel(float* __restrict__ ws) {
    const int jcode = blockIdx.x * 4 + (threadIdx.x >> 6);
    const int d     = threadIdx.x & 63;
    float v = ws[WS_ET + jcode * DIM + d];
    double sq = (double)v * (double)v;
    #pragma unroll
    for (int off = 32; off > 0; off >>= 1) sq += __shfl_down(sq, off, 64);
    if (d == 0) {
        ws[WS_ENORM + jcode] = (float)sq;
        ((double*)(ws + WS_EN64))[jcode] = sq;
    }
}

// ============================================================
// dist: MFMA bf16 3-term split + fused argmin/second-min.
// 256 threads = 4 waves; wave handles 32 rows x 512 codes.
// A fragments from global (registers), B fragments pre-packed in ws (L2).
// ============================================================
__global__ __launch_bounds__(256) void dist_kernel(const float* __restrict__ input,
                                                   float* __restrict__ ws) {
    const int tid  = threadIdx.x;
    const int lane = tid & 63;
    const int wv   = tid >> 6;
    const int r0   = blockIdx.x * 128 + wv * 32;
    const int n15  = lane & 15;
    const int koff = (lane >> 4) * 8;

    // ---- load + split A fragments: 2 row-subtiles x 2 K-steps ----
    short8_t Ahi[2][2], Alo[2][2];
    #pragma unroll
    for (int sub = 0; sub < 2; sub++) {
        const float* rp = input + (size_t)(r0 + sub * 16 + n15) * DIM + koff;
        #pragma unroll
        for (int s = 0; s < 2; s++) {
            float4 x0 = *(const float4*)(rp + s * 32);
            float4 x1 = *(const float4*)(rp + s * 32 + 4);
            float xf[8] = {x0.x, x0.y, x0.z, x0.w, x1.x, x1.y, x1.z, x1.w};
            short8_t h, l;
            #pragma unroll
            for (int e = 0; e < 8; e++) {
                ushort hb = f32_to_bf16_rn(xf[e]);
                float  lf = xf[e] - bf16_to_f32(hb);
                ushort lb = f32_to_bf16_rn(lf);
                h[e] = (short)hb;
                l[e] = (short)lb;
            }
            Ahi[sub][s] = h;
            Alo[sub][s] = l;
        }
    }

    const ushort* bhp = (const ushort*)(ws + WS_BH) + lane * 8;
    const ushort* blp = (const ushort*)(ws + WS_BL) + lane * 8;

    float m1[8], m2[8];
    int   j1[8];
    #pragma unroll
    for (int i = 0; i < 8; i++) { m1[i] = 3.4e38f; m2[i] = 3.4e38f; j1[i] = 0; }

    #pragma unroll 2
    for (int T = 0; T < 32; T++) {
        short8_t Bh0 = *(const short8_t*)(bhp + T * 1024);
        short8_t Bh1 = *(const short8_t*)(bhp + T * 1024 + 512);
        short8_t Bl0 = *(const short8_t*)(blp + T * 1024);
        short8_t Bl1 = *(const short8_t*)(blp + T * 1024 + 512);

        f32x4 aa = {0.f, 0.f, 0.f, 0.f};
        f32x4 ab = {0.f, 0.f, 0.f, 0.f};
        aa = __builtin_amdgcn_mfma_f32_16x16x32_bf16(Ahi[0][0], Bh0, aa, 0, 0, 0);
        ab = __builtin_amdgcn_mfma_f32_16x16x32_bf16(Ahi[1][0], Bh0, ab, 0, 0, 0);
        aa = __builtin_amdgcn_mfma_f32_16x16x32_bf16(Alo[0][0], Bh0, aa, 0, 0, 0);
        ab = __builtin_amdgcn_mfma_f32_16x16x32_bf16(Alo[1][0], Bh0, ab, 0, 0, 0);
        aa = __builtin_amdgcn_mfma_f32_16x16x32_bf16(Ahi[0][0], Bl0, aa, 0, 0, 0);
        ab = __builtin_amdgcn_mfma_f32_16x16x32_bf16(Ahi[1][0], Bl0, ab, 0, 0, 0);
        aa = __builtin_amdgcn_mfma_f32_16x16x32_bf16(Ahi[0][1], Bh1, aa, 0, 0, 0);
        ab = __builtin_amdgcn_mfma_f32_16x16x32_bf16(Ahi[1][1], Bh1, ab, 0, 0, 0);
        aa = __builtin_amdgcn_mfma_f32_16x16x32_bf16(Alo[0][1], Bh1, aa, 0, 0, 0);
        ab = __builtin_amdgcn_mfma_f32_16x16x32_bf16(Alo[1][1], Bh1, ab, 0, 0, 0);
        aa = __builtin_amdgcn_mfma_f32_16x16x32_bf16(Ahi[0][1], Bl1, aa, 0, 0, 0);
        ab = __builtin_amdgcn_mfma_f32_16x16x32_bf16(Ahi[1][1], Bl1, ab, 0, 0, 0);

        const float en = ws[WS_ENORM + T * 16 + n15];
        const int   jc = T * 16 + n15;
        #pragma unroll
        for (int q = 0; q < 4; q++) {
            float da = fmaf(-2.0f, aa[q], en);
            m2[q]    = fminf(m2[q], fmaxf(m1[q], da));
            j1[q]    = (da < m1[q]) ? jc : j1[q];
            m1[q]    = fminf(m1[q], da);
            float db = fmaf(-2.0f, ab[q], en);
            m2[q+4]  = fminf(m2[q+4], fmaxf(m1[q+4], db));
            j1[q+4]  = (db < m1[q+4]) ? jc : j1[q+4];
            m1[q+4]  = fminf(m1[q+4], db);
        }
    }

    // reduce across the 16 code-lanes (xor within low 4 lane bits)
    #pragma unroll
    for (int off = 1; off < 16; off <<= 1) {
        #pragma unroll
        for (int i = 0; i < 8; i++) {
            float b1 = __shfl_xor(m1[i], off, 64);
            float b2 = __shfl_xor(m2[i], off, 64);
            int   bj = __shfl_xor(j1[i], off, 64);
            float a1 = m1[i];
            float nm2 = fminf(fminf(m2[i], b2), fmaxf(a1, b1));
            bool takeB = (b1 < a1) || (b1 == a1 && bj < j1[i]);
            m1[i] = takeB ? b1 : a1;
            j1[i] = takeB ? bj : j1[i];
            m2[i] = nm2;
        }
    }

    if (n15 == 0) {
        #pragma unroll
        for (int i = 0; i < 8; i++) {
            int sub = i >> 2, q = i & 3;
            int r = r0 + sub * 16 + (lane >> 4) * 4 + q;
            ((int*)ws)[WS_IDX + r] = j1[i];
            if (m2[i] - m1[i] < GAP_THR) {
                int pos = atomicAdd((int*)ws + WS_RCNT, 1);
                ((int*)ws)[WS_RLIST + pos] = r;
            }
        }
    }
}

// ============================================================
// refine: fp64 re-resolution of near-tie rows (row staged in LDS,
// precomputed fp64 enorm).
// ============================================================
__global__ __launch_bounds__(64) void refine_kernel(const float* __restrict__ input,
                                                    float* __restrict__ ws) {
    __shared__ float rowf[DIM];
    const int cnt  = ((const int*)ws)[WS_RCNT];
    const int lane = threadIdx.x;
    const double* en64 = (const double*)(ws + WS_EN64);
    for (int ii = blockIdx.x; ii < cnt; ii += 512) {
        const int r = ((const int*)ws)[WS_RLIST + ii];
        __syncthreads();
        rowf[lane] = input[(size_t)r * DIM + lane];
        __syncthreads();
        double bd = 1e300;
        int    bj = 0x7fffffff;
        for (int kk = 0; kk < 8; kk++) {
            int j = kk * 64 + lane;
            const float* ep = ws + WS_ET + j * DIM;
            double s = 0.0;
            #pragma unroll 8
            for (int d = 0; d < DIM; d++)
                s = fma((double)ep[d], (double)rowf[d], s);
            double dist = en64[j] - 2.0 * s;
            if (dist < bd || (dist == bd && j < bj)) { bd = dist; bj = j; }
        }
        #pragma unroll
        for (int off = 32; off > 0; off >>= 1) {
            double od = __shfl_down(bd, off, 64);
            int    oj = __shfl_down(bj, off, 64);
            if (od < bd || (od == bd && oj < bj)) { bd = od; bj = oj; }
        }
        if (lane == 0) ((int*)ws)[WS_IDX + r] = bj;
    }
}

// ============================================================
// scatter: quantize gather + diff + embed_ind + LDS scatter-accumulate.
// 256 blocks x 512 threads; block owns 512 rows; wave processes 4 rows/iter
// with float4 lanes (fully coalesced).
// ============================================================
__global__ __launch_bounds__(512) void scatter_kernel(const float* __restrict__ input,
                                                      float* __restrict__ ws,
                                                      float* __restrict__ out,
                                                      int nslices) {
    __shared__ float loc[NE * 65];   // padded stride 65 to spread ds_add banks
    __shared__ float locc[NE];
    __shared__ float wsum[8];

    const int tid = threadIdx.x;
    for (int e = tid; e < NE * 65; e += 512) loc[e] = 0.0f;
    for (int e = tid; e < NE; e += 512) locc[e] = 0.0f;
    __syncthreads();

    const int lane = tid & 63;
    const int wv   = tid >> 6;
    const int rsub = lane >> 4;        // 0..3
    const int d4   = (lane & 15) * 4;  // dim quad
    const int base = blockIdx.x * 512;
    float dacc = 0.0f;

    for (int it = 0; it < 16; it++) {
        int r = base + (it * 8 + wv) * 4 + rsub;
        int j = ((const int*)ws)[WS_IDX + r];
        float4 in4 = *(const float4*)(input + (size_t)r * DIM + d4);
        float4 q4  = *(const float4*)(ws + WS_ET + j * DIM + d4);
        *(float4*)(out + Q_OFF + (size_t)r * DIM + d4) = q4;
        float dx = q4.x - in4.x, dy = q4.y - in4.y, dz = q4.z - in4.z, dw = q4.w - in4.w;
        dacc = fmaf(dx, dx, fmaf(dy, dy, fmaf(dz, dz, fmaf(dw, dw, dacc))));
        atomicAdd(&loc[j * 65 + d4 + 0], in4.x);
        atomicAdd(&loc[j * 65 + d4 + 1], in4.y);
        atomicAdd(&loc[j * 65 + d4 + 2], in4.z);
        atomicAdd(&loc[j * 65 + d4 + 3], in4.w);
        if ((lane & 15) == 0) {
            atomicAdd(&locc[j], 1.0f);
            out[IND_OFF + r] = (float)j;
        }
    }
    __syncthreads();

    // flush partials
    if (nslices == NBLK_SC) {
        float* part = ws + WS_PART + (size_t)blockIdx.x * PART_STRIDE;
        for (int e = tid; e < NE * DIM; e += 512) part[e] = loc[(e >> 6) * 65 + (e & 63)];
        for (int e = tid; e < NE; e += 512) part[NE * DIM + e] = locc[e];
    } else {
        float* part = ws + WS_PART + (size_t)(blockIdx.x % nslices) * PART_STRIDE;
        for (int e = tid; e < NE * DIM; e += 512) atomicAdd(&part[e], loc[(e >> 6) * 65 + (e & 63)]);
        for (int e = tid; e < NE; e += 512) atomicAdd(&part[NE * DIM + e], locc[e]);
    }

    // diff reduction
    #pragma unroll
    for (int off = 32; off > 0; off >>= 1) dacc += __shfl_down(dacc, off, 64);
    if (lane == 0) wsum[wv] = dacc;
    __syncthreads();
    if (tid == 0) {
        float s = 0.0f;
        #pragma unroll
        for (int k = 0; k < 8; k++) s += wsum[k];
        atomicAdd(&ws[WS_DIFF], s);
    }
}

// ============================================================
// reduce: sum partials; write new_cluster_size + new_embed_avg.
// ============================================================
__global__ __launch_bounds__(256) void reduce_kernel(const float* __restrict__ cluster_size,
                                                     const float* __restrict__ embed_avg,
                                                     const float* __restrict__ ws,
                                                     float* __restrict__ out,
                                                     int nslices) {
    int e = blockIdx.x * 256 + threadIdx.x;
    if (e >= PART_STRIDE) return;
    float s = 0.0f;
    const float* p = ws + WS_PART + e;
    for (int b = 0; b < nslices; b++) s += p[(size_t)b * PART_STRIDE];
    if (e < NE * DIM) {
        int j = e >> 6, d = e & 63;
        out[AVG_OFF + d * NE + j] = fmaf(embed_avg[d * NE + j], DECAYF, OMDECAY * s);
    } else {
        int j = e - NE * DIM;
        out[CS_OFF + j] = fmaf(cluster_size[j], DECAYF, OMDECAY * s);
    }
}

// ============================================================
// finalize1 (1 block): n, cs divisor, diff.
// ============================================================
__global__ __launch_bounds__(512) void finalize1_kernel(float* __restrict__ ws,
                                                        float* __restrict__ out) {
    __shared__ float red[8];
    const int t = threadIdx.x;
    float v = out[CS_OFF + t];
    float s = v;
    #pragma unroll
    for (int off = 32; off > 0; off >>= 1) s += __shfl_down(s, off, 64);
    if ((t & 63) == 0) red[t >> 6] = s;
    __syncthreads();
    float n = red[0] + red[1] + red[2] + red[3] + red[4] + red[5] + red[6] + red[7];
    ws[WS_CSDIV + t] = (v + EPSF) / (n + (float)NE * EPSF) * n;
    if (t == 0) out[DIFF_OFF] = ws[WS_DIFF] * (1.0f / 8388608.0f);
}

// ============================================================
// finalize2: new_embed = new_embed_avg / cs  (grid-wide).
// ============================================================
__global__ __launch_bounds__(512) void finalize2_kernel(const float* __restrict__ ws,
                                                        float* __restrict__ out) {
    int e = blockIdx.x * 512 + threadIdx.x;
    out[EMB_OFF + e] = out[AVG_OFF + e] / ws[WS_CSDIV + (e & (NE - 1))];
}

// ============================================================
extern "C" void kernel_launch(void* const* d_in, const int* in_sizes, int n_in,
                              void* d_out, int out_size, void* d_ws, size_t ws_size,
                              hipStream_t stream) {
    const float* input        = (const float*)d_in[0];
    const float* embed        = (const float*)d_in[1];
    const float* cluster_size = (const float*)d_in[2];
    const float* embed_avg    = (const float*)d_in[3];
    float* out = (float*)d_out;
    float* ws  = (float*)d_ws;

    int nslices = NBLK_SC;
    size_t needed = ((size_t)WS_PART + (size_t)NBLK_SC * PART_STRIDE) * 4ull;
    if (ws_size < needed) {
        size_t avail_f = ws_size / 4;
        size_t room = (avail_f > WS_PART) ? (avail_f - WS_PART) : 0;
        long long k = (long long)(room / PART_STRIDE);
        nslices = (int)(k < 1 ? 1 : (k > NBLK_SC ? NBLK_SC : k));
    }
    int zero_cnt = (nslices == NBLK_SC) ? 0 : nslices * PART_STRIDE;

    prep1_kernel<<<64, 512, 0, stream>>>(embed, ws, zero_cnt);
    prep2_kernel<<<128, 256, 0, stream>>>(ws);
    dist_kernel<<<N_ROWS / 128, 256, 0, stream>>>(input, ws);
    refine_kernel<<<512, 64, 0, stream>>>(input, ws);
    scatter_kernel<<<NBLK_SC, 512, 0, stream>>>(input, ws, out, nslices);
    reduce_kernel<<<(PART_STRIDE + 255) / 256, 256, 0, stream>>>(cluster_size, embed_avg, ws, out, nslices);
    finalize1_kernel<<<1, 512, 0, stream>>>(ws, out);
    finalize2_kernel<<<64, 512, 0, stream>>>(ws, out);
}

// Round 3
// 147.180 us; speedup vs baseline: 2.2201x; 1.3316x over previous
//
#include <hip/hip_runtime.h>

typedef __attribute__((ext_vector_type(8))) short short8_t;
typedef __attribute__((ext_vector_type(4))) float f32x4;

// ---------------- problem constants ----------------
#define N_ROWS   131072     // 32*64*64
#define DIM      64
#define NE       512
#define DECAYF   0.99f
#define OMDECAY  0.01f
#define EPSF     1e-5f
#define GAP_THR  0.02f

// ---------------- d_out offsets (floats) ----------------
#define Q_OFF    0            // 8388608
#define DIFF_OFF 8388608      // 1
#define IND_OFF  8388609      // 131072
#define CS_OFF   8519681      // 512
#define AVG_OFF  8520193      // 32768
#define EMB_OFF  8552961      // 32768

// ---------------- ws offsets (floats) ----------------
#define WS_ET     0            // 32768 : ET fp32 [code][dim]
#define WS_ENORM  32768        // 512   : ||E_j||^2 fp32
#define WS_EN64   33280        // 1024  : ||E_j||^2 fp64 (512 doubles, 8B aligned)
#define WS_CSDIV  34304        // 512   : cs divisor
#define WS_DIFF   34816        // 1
#define WS_RCNT   34817        // 1 (int)
#define WS_IDX    34818        // 131072 (int)
#define WS_RLIST  165890       // 131072 (int)
#define WS_BH     296964       // 16384 floats = 32768 ushort: packed bf16 hi B-fragments
#define WS_BL     313348       // 16384 floats = 32768 ushort: packed bf16 lo B-fragments
#define WS_PART   329732       // nslices * PART_STRIDE
// PART layout (output-major): e in [0,32768): d=e>>9, j=e&511 -> esum[j][d]
//                             e in [32768,33280): counts[j]
#define PART_STRIDE 33280
#define NBLK_SC  256           // scatter blocks (= max slices)
#define NGRP     16            // reduction tree fan-in groups

__device__ __forceinline__ ushort f32_to_bf16_rn(float f) {
    unsigned u = __float_as_uint(f);
    unsigned r = (u + 0x7FFFu + ((u >> 16) & 1u)) >> 16;
    return (ushort)r;
}
__device__ __forceinline__ float bf16_to_f32(ushort h) {
    return __uint_as_float(((unsigned)h) << 16);
}

// ============================================================
// prep1: transpose embed -> ET fp32; build packed bf16 hi/lo B-fragment
// images in per-lane register order; zero small accumulators.
// grid 64 blocks (d) x 512 threads (c): coalesced embed read.
// ============================================================
__global__ __launch_bounds__(512) void prep1_kernel(const float* __restrict__ embed,
                                                    float* __restrict__ ws,
                                                    int zero_cnt) {
    const int d = blockIdx.x;    // dim 0..63
    const int c = threadIdx.x;   // code 0..511
    float v = embed[d * NE + c];
    ws[WS_ET + c * DIM + d] = v;

    ushort hb = f32_to_bf16_rn(v);
    float  lf = v - bf16_to_f32(hb);
    ushort lb = f32_to_bf16_rn(lf);

    // fragment order: tile T=c>>4, n=c&15, kstep s=d>>5, k8=(d>>3)&3, j=d&7
    const int T  = c >> 4;
    const int n  = c & 15;
    const int s  = d >> 5;
    const int k8 = (d >> 3) & 3;
    const int j  = d & 7;
    const int l  = k8 * 16 + n;
    const int idx = (T * 2 + s) * 512 + l * 8 + j;
    ((ushort*)(ws + WS_BH))[idx] = hb;
    ((ushort*)(ws + WS_BL))[idx] = lb;

    if (d == 0 && c == 0) {
        ws[WS_DIFF] = 0.0f;
        ((int*)ws)[WS_RCNT] = 0;
    }
    // fallback-path zeroing of partial slices
    int gid = blockIdx.x * 512 + threadIdx.x;   // 0..32767
    for (int e = gid; e < zero_cnt; e += 64 * 512)
        ws[WS_PART + e] = 0.0f;
}

// ============================================================
// prep2: enorm fp32 + fp64 from ET (coalesced). wave per code.
// ============================================================
__global__ __launch_bounds__(256) void prep2_kernel(float* __restrict__ ws) {
    const int jcode = blockIdx.x * 4 + (threadIdx.x >> 6);
    const int d     = threadIdx.x & 63;
    float v = ws[WS_ET + jcode * DIM + d];
    double sq = (double)v * (double)v;
    #pragma unroll
    for (int off = 32; off > 0; off >>= 1) sq += __shfl_down(sq, off, 64);
    if (d == 0) {
        ws[WS_ENORM + jcode] = (float)sq;
        ((double*)(ws + WS_EN64))[jcode] = sq;
    }
}

// ============================================================
// dist: MFMA bf16 3-term split + fused argmin/second-min.
// 256 threads = 4 waves; wave handles 32 rows x 512 codes.
// ============================================================
__global__ __launch_bounds__(256) void dist_kernel(const float* __restrict__ input,
                                                   float* __restrict__ ws) {
    const int tid  = threadIdx.x;
    const int lane = tid & 63;
    const int wv   = tid >> 6;
    const int r0   = blockIdx.x * 128 + wv * 32;
    const int n15  = lane & 15;
    const int koff = (lane >> 4) * 8;

    // ---- load + split A fragments: 2 row-subtiles x 2 K-steps ----
    short8_t Ahi[2][2], Alo[2][2];
    #pragma unroll
    for (int sub = 0; sub < 2; sub++) {
        const float* rp = input + (size_t)(r0 + sub * 16 + n15) * DIM + koff;
        #pragma unroll
        for (int s = 0; s < 2; s++) {
            float4 x0 = *(const float4*)(rp + s * 32);
            float4 x1 = *(const float4*)(rp + s * 32 + 4);
            float xf[8] = {x0.x, x0.y, x0.z, x0.w, x1.x, x1.y, x1.z, x1.w};
            short8_t h, l;
            #pragma unroll
            for (int e = 0; e < 8; e++) {
                ushort hb = f32_to_bf16_rn(xf[e]);
                float  lf = xf[e] - bf16_to_f32(hb);
                ushort lb = f32_to_bf16_rn(lf);
                h[e] = (short)hb;
                l[e] = (short)lb;
            }
            Ahi[sub][s] = h;
            Alo[sub][s] = l;
        }
    }

    const ushort* bhp = (const ushort*)(ws + WS_BH) + lane * 8;
    const ushort* blp = (const ushort*)(ws + WS_BL) + lane * 8;

    float m1[8], m2[8];
    int   j1[8];
    #pragma unroll
    for (int i = 0; i < 8; i++) { m1[i] = 3.4e38f; m2[i] = 3.4e38f; j1[i] = 0; }

    #pragma unroll 2
    for (int T = 0; T < 32; T++) {
        short8_t Bh0 = *(const short8_t*)(bhp + T * 1024);
        short8_t Bh1 = *(const short8_t*)(bhp + T * 1024 + 512);
        short8_t Bl0 = *(const short8_t*)(blp + T * 1024);
        short8_t Bl1 = *(const short8_t*)(blp + T * 1024 + 512);

        f32x4 aa = {0.f, 0.f, 0.f, 0.f};
        f32x4 ab = {0.f, 0.f, 0.f, 0.f};
        aa = __builtin_amdgcn_mfma_f32_16x16x32_bf16(Ahi[0][0], Bh0, aa, 0, 0, 0);
        ab = __builtin_amdgcn_mfma_f32_16x16x32_bf16(Ahi[1][0], Bh0, ab, 0, 0, 0);
        aa = __builtin_amdgcn_mfma_f32_16x16x32_bf16(Alo[0][0], Bh0, aa, 0, 0, 0);
        ab = __builtin_amdgcn_mfma_f32_16x16x32_bf16(Alo[1][0], Bh0, ab, 0, 0, 0);
        aa = __builtin_amdgcn_mfma_f32_16x16x32_bf16(Ahi[0][0], Bl0, aa, 0, 0, 0);
        ab = __builtin_amdgcn_mfma_f32_16x16x32_bf16(Ahi[1][0], Bl0, ab, 0, 0, 0);
        aa = __builtin_amdgcn_mfma_f32_16x16x32_bf16(Ahi[0][1], Bh1, aa, 0, 0, 0);
        ab = __builtin_amdgcn_mfma_f32_16x16x32_bf16(Ahi[1][1], Bh1, ab, 0, 0, 0);
        aa = __builtin_amdgcn_mfma_f32_16x16x32_bf16(Alo[0][1], Bh1, aa, 0, 0, 0);
        ab = __builtin_amdgcn_mfma_f32_16x16x32_bf16(Alo[1][1], Bh1, ab, 0, 0, 0);
        aa = __builtin_amdgcn_mfma_f32_16x16x32_bf16(Ahi[0][1], Bl1, aa, 0, 0, 0);
        ab = __builtin_amdgcn_mfma_f32_16x16x32_bf16(Ahi[1][1], Bl1, ab, 0, 0, 0);

        const float en = ws[WS_ENORM + T * 16 + n15];
        const int   jc = T * 16 + n15;
        #pragma unroll
        for (int q = 0; q < 4; q++) {
            float da = fmaf(-2.0f, aa[q], en);
            m2[q]    = fminf(m2[q], fmaxf(m1[q], da));
            j1[q]    = (da < m1[q]) ? jc : j1[q];
            m1[q]    = fminf(m1[q], da);
            float db = fmaf(-2.0f, ab[q], en);
            m2[q+4]  = fminf(m2[q+4], fmaxf(m1[q+4], db));
            j1[q+4]  = (db < m1[q+4]) ? jc : j1[q+4];
            m1[q+4]  = fminf(m1[q+4], db);
        }
    }

    // reduce across the 16 code-lanes (xor within low 4 lane bits)
    #pragma unroll
    for (int off = 1; off < 16; off <<= 1) {
        #pragma unroll
        for (int i = 0; i < 8; i++) {
            float b1 = __shfl_xor(m1[i], off, 64);
            float b2 = __shfl_xor(m2[i], off, 64);
            int   bj = __shfl_xor(j1[i], off, 64);
            float a1 = m1[i];
            float nm2 = fminf(fminf(m2[i], b2), fmaxf(a1, b1));
            bool takeB = (b1 < a1) || (b1 == a1 && bj < j1[i]);
            m1[i] = takeB ? b1 : a1;
            j1[i] = takeB ? bj : j1[i];
            m2[i] = nm2;
        }
    }

    if (n15 == 0) {
        #pragma unroll
        for (int i = 0; i < 8; i++) {
            int sub = i >> 2, q = i & 3;
            int r = r0 + sub * 16 + (lane >> 4) * 4 + q;
            ((int*)ws)[WS_IDX + r] = j1[i];
            if (m2[i] - m1[i] < GAP_THR) {
                int pos = atomicAdd((int*)ws + WS_RCNT, 1);
                ((int*)ws)[WS_RLIST + pos] = r;
            }
        }
    }
}

// ============================================================
// refine: fp64 re-resolution of near-tie rows.
// ============================================================
__global__ __launch_bounds__(64) void refine_kernel(const float* __restrict__ input,
                                                    float* __restrict__ ws) {
    __shared__ float rowf[DIM];
    const int cnt  = ((const int*)ws)[WS_RCNT];
    const int lane = threadIdx.x;
    const double* en64 = (const double*)(ws + WS_EN64);
    for (int ii = blockIdx.x; ii < cnt; ii += 512) {
        const int r = ((const int*)ws)[WS_RLIST + ii];
        __syncthreads();
        rowf[lane] = input[(size_t)r * DIM + lane];
        __syncthreads();
        double bd = 1e300;
        int    bj = 0x7fffffff;
        for (int kk = 0; kk < 8; kk++) {
            int j = kk * 64 + lane;
            const float* ep = ws + WS_ET + j * DIM;
            double s = 0.0;
            #pragma unroll 8
            for (int d = 0; d < DIM; d++)
                s = fma((double)ep[d], (double)rowf[d], s);
            double dist = en64[j] - 2.0 * s;
            if (dist < bd || (dist == bd && j < bj)) { bd = dist; bj = j; }
        }
        #pragma unroll
        for (int off = 32; off > 0; off >>= 1) {
            double od = __shfl_down(bd, off, 64);
            int    oj = __shfl_down(bj, off, 64);
            if (od < bd || (od == bd && oj < bj)) { bd = od; bj = oj; }
        }
        if (lane == 0) ((int*)ws)[WS_IDX + r] = bj;
    }
}

// ============================================================
// scatter: quantize gather + diff + embed_ind + LDS scatter-accumulate.
// 256 blocks x 512 threads; block owns 512 rows.
// Flush is TRANSPOSED to output-major (e = d*512 + j): LDS stride-65 reads
// are bank-conflict-free (2-way), global writes coalesced.
// ============================================================
__global__ __launch_bounds__(512) void scatter_kernel(const float* __restrict__ input,
                                                      float* __restrict__ ws,
                                                      float* __restrict__ out,
                                                      int nslices) {
    __shared__ float loc[NE * 65];   // [j][d] padded stride 65
    __shared__ float locc[NE];
    __shared__ float wsum[8];

    const int tid = threadIdx.x;
    for (int e = tid; e < NE * 65; e += 512) loc[e] = 0.0f;
    for (int e = tid; e < NE; e += 512) locc[e] = 0.0f;
    __syncthreads();

    const int lane = tid & 63;
    const int wv   = tid >> 6;
    const int rsub = lane >> 4;        // 0..3
    const int d4   = (lane & 15) * 4;  // dim quad
    const int base = blockIdx.x * 512;
    float dacc = 0.0f;

    for (int it = 0; it < 16; it++) {
        int r = base + (it * 8 + wv) * 4 + rsub;
        int j = ((const int*)ws)[WS_IDX + r];
        float4 in4 = *(const float4*)(input + (size_t)r * DIM + d4);
        float4 q4  = *(const float4*)(ws + WS_ET + j * DIM + d4);
        *(float4*)(out + Q_OFF + (size_t)r * DIM + d4) = q4;
        float dx = q4.x - in4.x, dy = q4.y - in4.y, dz = q4.z - in4.z, dw = q4.w - in4.w;
        dacc = fmaf(dx, dx, fmaf(dy, dy, fmaf(dz, dz, fmaf(dw, dw, dacc))));
        atomicAdd(&loc[j * 65 + d4 + 0], in4.x);
        atomicAdd(&loc[j * 65 + d4 + 1], in4.y);
        atomicAdd(&loc[j * 65 + d4 + 2], in4.z);
        atomicAdd(&loc[j * 65 + d4 + 3], in4.w);
        if ((lane & 15) == 0) {
            atomicAdd(&locc[j], 1.0f);
            out[IND_OFF + r] = (float)j;
        }
    }
    __syncthreads();

    // flush partials (output-major: e = d*512 + j)
    if (nslices == NBLK_SC) {
        float* part = ws + WS_PART + (size_t)blockIdx.x * PART_STRIDE;
        for (int e = tid; e < NE * DIM; e += 512) part[e] = loc[(e & 511) * 65 + (e >> 9)];
        for (int e = tid; e < NE; e += 512) part[NE * DIM + e] = locc[e];
    } else {
        float* part = ws + WS_PART + (size_t)(blockIdx.x % nslices) * PART_STRIDE;
        for (int e = tid; e < NE * DIM; e += 512) atomicAdd(&part[e], loc[(e & 511) * 65 + (e >> 9)]);
        for (int e = tid; e < NE; e += 512) atomicAdd(&part[NE * DIM + e], locc[e]);
    }

    // diff reduction
    #pragma unroll
    for (int off = 32; off > 0; off >>= 1) dacc += __shfl_down(dacc, off, 64);
    if (lane == 0) wsum[wv] = dacc;
    __syncthreads();
    if (tid == 0) {
        float s = 0.0f;
        #pragma unroll
        for (int k = 0; k < 8; k++) s += wsum[k];
        atomicAdd(&ws[WS_DIFF], s);
    }
}

// ============================================================
// reduce1: group tree reduction, IN PLACE. Group g sums slices
// g, g+NGRP, g+2*NGRP, ... into slice g. float4 per thread.
// grid (ceil(PART_STRIDE/4/256), NGRP).
// ============================================================
__global__ __launch_bounds__(256) void reduce1_kernel(float* __restrict__ ws,
                                                      int nslices) {
    const int ef = blockIdx.x * 256 + threadIdx.x;   // float4 index
    const int g  = blockIdx.y;
    if (ef >= PART_STRIDE / 4 || g >= nslices) return;
    float4 acc = {0.f, 0.f, 0.f, 0.f};
    for (int s = g; s < nslices; s += NGRP) {
        float4 v = *(const float4*)(ws + WS_PART + (size_t)s * PART_STRIDE + ef * 4);
        acc.x += v.x; acc.y += v.y; acc.z += v.z; acc.w += v.w;
    }
    *(float4*)(ws + WS_PART + (size_t)g * PART_STRIDE + ef * 4) = acc;
}

// ============================================================
// reduce2: sum the NGRP group slices + fused EMA. Fully coalesced
// (partials are output-major).
// ============================================================
__global__ __launch_bounds__(256) void reduce2_kernel(const float* __restrict__ cluster_size,
                                                      const float* __restrict__ embed_avg,
                                                      const float* __restrict__ ws,
                                                      float* __restrict__ out,
                                                      int ngrp) {
    const int e = blockIdx.x * 256 + threadIdx.x;
    if (e >= PART_STRIDE) return;
    float s = 0.0f;
    const float* p = ws + WS_PART + e;
    for (int g = 0; g < ngrp; g++) s += p[(size_t)g * PART_STRIDE];
    if (e < NE * DIM) {
        out[AVG_OFF + e] = fmaf(embed_avg[e], DECAYF, OMDECAY * s);
    } else {
        int j = e - NE * DIM;
        out[CS_OFF + j] = fmaf(cluster_size[j], DECAYF, OMDECAY * s);
    }
}

// ============================================================
// finalize1 (1 block): n, cs divisor, diff.
// ============================================================
__global__ __launch_bounds__(512) void finalize1_kernel(float* __restrict__ ws,
                                                        float* __restrict__ out) {
    __shared__ float red[8];
    const int t = threadIdx.x;
    float v = out[CS_OFF + t];
    float s = v;
    #pragma unroll
    for (int off = 32; off > 0; off >>= 1) s += __shfl_down(s, off, 64);
    if ((t & 63) == 0) red[t >> 6] = s;
    __syncthreads();
    float n = red[0] + red[1] + red[2] + red[3] + red[4] + red[5] + red[6] + red[7];
    ws[WS_CSDIV + t] = (v + EPSF) / (n + (float)NE * EPSF) * n;
    if (t == 0) out[DIFF_OFF] = ws[WS_DIFF] * (1.0f / 8388608.0f);
}

// ============================================================
// finalize2: new_embed = new_embed_avg / cs  (grid-wide).
// ============================================================
__global__ __launch_bounds__(512) void finalize2_kernel(const float* __restrict__ ws,
                                                        float* __restrict__ out) {
    int e = blockIdx.x * 512 + threadIdx.x;
    out[EMB_OFF + e] = out[AVG_OFF + e] / ws[WS_CSDIV + (e & (NE - 1))];
}

// ============================================================
extern "C" void kernel_launch(void* const* d_in, const int* in_sizes, int n_in,
                              void* d_out, int out_size, void* d_ws, size_t ws_size,
                              hipStream_t stream) {
    const float* input        = (const float*)d_in[0];
    const float* embed        = (const float*)d_in[1];
    const float* cluster_size = (const float*)d_in[2];
    const float* embed_avg    = (const float*)d_in[3];
    float* out = (float*)d_out;
    float* ws  = (float*)d_ws;

    int nslices = NBLK_SC;
    size_t needed = ((size_t)WS_PART + (size_t)NBLK_SC * PART_STRIDE) * 4ull;
    if (ws_size < needed) {
        size_t avail_f = ws_size / 4;
        size_t room = (avail_f > WS_PART) ? (avail_f - WS_PART) : 0;
        long long k = (long long)(room / PART_STRIDE);
        nslices = (int)(k < 1 ? 1 : (k > NBLK_SC ? NBLK_SC : k));
    }
    int zero_cnt = (nslices == NBLK_SC) ? 0 : nslices * PART_STRIDE;
    int ngrp = nslices < NGRP ? nslices : NGRP;

    prep1_kernel<<<64, 512, 0, stream>>>(embed, ws, zero_cnt);
    prep2_kernel<<<128, 256, 0, stream>>>(ws);
    dist_kernel<<<N_ROWS / 128, 256, 0, stream>>>(input, ws);
    refine_kernel<<<512, 64, 0, stream>>>(input, ws);
    scatter_kernel<<<NBLK_SC, 512, 0, stream>>>(input, ws, out, nslices);
    reduce1_kernel<<<dim3((PART_STRIDE / 4 + 255) / 256, NGRP), 256, 0, stream>>>(ws, nslices);
    reduce2_kernel<<<(PART_STRIDE + 255) / 256, 256, 0, stream>>>(cluster_size, embed_avg, ws, out, ngrp);
    finalize1_kernel<<<1, 512, 0, stream>>>(ws, out);
    finalize2_kernel<<<64, 512, 0, stream>>>(ws, out);
}